// Round 24
// baseline (828.654 us; speedup 1.0000x reference)
//
#include <hip/hip_runtime.h>
#include <cmath>

#define Hn 512
#define Wn 512
#define Bn 32
#define BANDS 16
#define BH 32                       // output rows per band
#define SW 256                      // strip width (output cols per block)
#define NE (SW + 8)                 // staged entries per row (264)
#define NBLK (Bn * BANDS * 2)       // 1024 blocks
#define NT 256                      // 4 waves per block

struct GaussW { float g[9]; };

__device__ __forceinline__ void load3(
    const float* __restrict__ pir, const float* __restrict__ pvi,
    const float* __restrict__ pfu, int y, int xs,
    float& a, float& v, float& f)
{
    bool ok = ((unsigned)y < (unsigned)Hn) && ((unsigned)xs < (unsigned)Wn);
    size_t o = ok ? ((size_t)y * Wn + xs) : 0;
    float aa = pir[o], vv = pvi[o], ff = pfu[o];
    a = ok ? aa : 0.f;  v = ok ? vv : 0.f;  f = ok ? ff : 0.f;
}

__device__ __forceinline__ void stage_row(
    float4* rowq, int e, float a, float v, float f)
{
    float di = a - f, dv = v - f;
    rowq[e] = make_float4(a, v, di * di, dv * dv);
}

// horizontal 9-tap from LDS + in-register vertical update. j/emit are
// compile-time after full unroll (rule #20). pd computed at tap.
__device__ __forceinline__ void compute_row(
    const float4* rowq, int x, int j, bool emit,
    float mk, const GaussW& gw,
    float* hb_i, float* hb_v, float* ag_i, float* ag_v, float* ag_q,
    float& Sbi, float& Sbv, float& acc)
{
    float bi = 0.f, bv = 0.f, ga = 0.f, gv = 0.f, qd = 0.f;
    #pragma unroll
    for (int i = 0; i < 9; ++i) {
        float4 q = rowq[x + i];
        float gg = gw.g[i];
        bi += q.z;  bv += q.w;
        ga = fmaf(gg, q.x, ga);
        gv = fmaf(gg, q.y, gv);
        qd = fmaf(gg, (q.x - q.y) * (q.x + q.y), qd);   // pd = a^2 - v^2
    }
    Sbi += bi - hb_i[j];  hb_i[j] = bi;
    Sbv += bv - hb_v[j];  hb_v[j] = bv;
    float mi = 0.f, mv = 0.f, mq = 0.f;
    const float g8 = gw.g[8];
    #pragma unroll
    for (int s = 0; s < 9; ++s) {
        if (s == j) {
            mi = fmaf(g8, ga, ag_i[j]);
            mv = fmaf(g8, gv, ag_v[j]);
            mq = fmaf(g8, qd, ag_q[j]);
        } else {
            float w = gw.g[(j - s - 1 + 9) % 9];
            ag_i[s] = fmaf(w, ga, ag_i[s]);
            ag_v[s] = fmaf(w, gv, ag_v[s]);
            ag_q[s] = fmaf(w, qd, ag_q[s]);
        }
    }
    ag_i[j] = 0.f; ag_v[j] = 0.f; ag_q[j] = 0.f;
    if (emit) {
        float dvar = mq - (mi - mv) * (mi + mv);   // var_i - var_v
        float m1  = (dvar > 0.f) ? 1.f : 0.f;
        float sel = (m1 + mk > 0.f) ? 1.f : 0.f;
        acc += sel * (Sbi * (1.f / 81.f)) + (1.f - sel) * (Sbv * (1.f / 81.f));
    }
}

// R24 = R22 body, block geometry split for drift: 256-col strips x 32-row
// bands -> 1024 blocks x 4 waves, LDS 17KB -> 4 independent blocks/CU (same
// 16 waves/CU but 4 separate barrier clocks). R22/R23 analysis: LDS pipe is
// the dominant stream (~3840 of 6240 cyc/phase) at only ~62% utilization --
// the loss is 8-wave barrier lockstep burstiness. Threads t<8 double-duty
// the 8 x-halo entries (+6 staging regs; WRITE_SIZE is the spill tripwire).
__global__ __launch_bounds__(NT) void fuse_loss_kernel(
    const float* __restrict__ vis, const float* __restrict__ ir,
    const float* __restrict__ fus, const float* __restrict__ mask,
    float* __restrict__ ws, GaussW gw)
{
    __shared__ __align__(16) float4 s_q[2][2][NE];   // 16896 B
    __shared__ float s_part[4];

    const int t     = threadIdx.x;
    const int b     = blockIdx.x;
    const int img   = b >> 5;
    const int band  = (b >> 1) & 15;
    const int strip = b & 1;
    const int X0    = strip * SW;
    const int Y0    = band * BH;
    const int xsm   = X0 + t - 4;        // main staged col (entry t)
    const bool hh   = (t < 8);
    const int xsh   = X0 + SW + t - 4;   // halo staged col (entry SW+t)
    const int xo    = X0 + t;            // output col (always valid)

    const size_t ibase = (size_t)img * (size_t)(Hn * Wn);
    const float* pir = ir  + ibase;
    const float* pvi = vis + ibase;
    const float* pfu = fus + ibase;
    const float* pmk = mask + ibase;

    // vertical state (statically indexed after unroll)
    float hb_i[9], hb_v[9], ag_i[9], ag_v[9], ag_q[9];
    #pragma unroll
    for (int s = 0; s < 9; ++s) {
        hb_i[s] = 0.f; hb_v[s] = 0.f;
        ag_i[s] = 0.f; ag_v[s] = 0.f; ag_q[s] = 0.f;
    }
    float Sbi = 0.f, Sbv = 0.f, acc = 0.f;

    // prologue: rows r=0,1 (y=Y0-4,Y0-3) -> buf0; preload rows r=2,3
    float aA, vA, fA, aB, vB, fB;
    float aAh = 0.f, vAh = 0.f, fAh = 0.f, aBh = 0.f, vBh = 0.f, fBh = 0.f;
    if (hh) load3(pir, pvi, pfu, Y0 - 4, xsh, aAh, vAh, fAh);
    if (hh) load3(pir, pvi, pfu, Y0 - 3, xsh, aBh, vBh, fBh);
    load3(pir, pvi, pfu, Y0 - 4, xsm, aA, vA, fA);
    load3(pir, pvi, pfu, Y0 - 3, xsm, aB, vB, fB);
    stage_row(s_q[0][0], t, aA, vA, fA);
    stage_row(s_q[0][1], t, aB, vB, fB);
    if (hh) stage_row(s_q[0][0], SW + t, aAh, vAh, fAh);
    if (hh) stage_row(s_q[0][1], SW + t, aBh, vBh, fBh);
    if (hh) load3(pir, pvi, pfu, Y0 - 2, xsh, aAh, vAh, fAh);
    if (hh) load3(pir, pvi, pfu, Y0 - 1, xsh, aBh, vBh, fBh);
    load3(pir, pvi, pfu, Y0 - 2, xsm, aA, vA, fA);
    load3(pir, pvi, pfu, Y0 - 1, xsm, aB, vB, fB);
    float mkA = 0.f, mkB = 0.f;
    __syncthreads();

    #pragma unroll
    for (int p = 0; p < 20; ++p) {
        const int cur = p & 1;
        // stage rows 2p+2, 2p+3 (preloaded last iter) into the other buffer
        if (p < 19) {
            stage_row(s_q[cur ^ 1][0], t, aA, vA, fA);
            stage_row(s_q[cur ^ 1][1], t, aB, vB, fB);
            if (hh) stage_row(s_q[cur ^ 1][0], SW + t, aAh, vAh, fAh);
            if (hh) stage_row(s_q[cur ^ 1][1], SW + t, aBh, vBh, fBh);
        }
        // issue loads for rows 2p+4, 2p+5 (consumed next iter); halo first
        if (p < 18) {
            if (hh) load3(pir, pvi, pfu, Y0 + 2 * p,     xsh, aAh, vAh, fAh);
            if (hh) load3(pir, pvi, pfu, Y0 + 2 * p + 1, xsh, aBh, vBh, fBh);
            load3(pir, pvi, pfu, Y0 + 2 * p,     xsm, aA, vA, fA);
            load3(pir, pvi, pfu, Y0 + 2 * p + 1, xsm, aB, vB, fB);
        }
        // compute rows r=2p, 2p+1 from buf[cur]; emit when r>=8
        compute_row(s_q[cur][0], t, (2 * p) % 9,     (p >= 4),
                    mkA, gw, hb_i, hb_v, ag_i, ag_v, ag_q, Sbi, Sbv, acc);
        compute_row(s_q[cur][1], t, (2 * p + 1) % 9, (p >= 4),
                    mkB, gw, hb_i, hb_v, ag_i, ag_v, ag_q, Sbi, Sbv, acc);
        // issue mask loads for pair p+1's emit rows
        if (p >= 3 && p < 19) {
            mkA = pmk[(size_t)(Y0 + 2 * p - 6) * Wn + xo];
            mkB = pmk[(size_t)(Y0 + 2 * p - 5) * Wn + xo];
        }
        __syncthreads();
    }

    // block reduction -> one partial per block
    #pragma unroll
    for (int off = 32; off > 0; off >>= 1)
        acc += __shfl_down(acc, off, 64);
    if ((t & 63) == 0) s_part[t >> 6] = acc;
    __syncthreads();
    if (t == 0)
        ws[b] = s_part[0] + s_part[1] + s_part[2] + s_part[3];
}

__global__ __launch_bounds__(256) void reduce_kernel(const float* __restrict__ ws,
                                                     float* __restrict__ out)
{
    __shared__ float sp[4];
    int t = threadIdx.x;
    float v = 0.f;
    for (int i = t; i < NBLK; i += 256) v += ws[i];
    #pragma unroll
    for (int off = 32; off > 0; off >>= 1)
        v += __shfl_down(v, off, 64);
    if ((t & 63) == 0) sp[t >> 6] = v;
    __syncthreads();
    if (t == 0)
        out[0] = (sp[0] + sp[1] + sp[2] + sp[3]) * (1.f / ((float)Bn * Hn * Wn));
}

extern "C" void kernel_launch(void* const* d_in, const int* in_sizes, int n_in,
                              void* d_out, int out_size, void* d_ws, size_t ws_size,
                              hipStream_t stream) {
    const float* vis  = (const float*)d_in[0];
    const float* ir   = (const float*)d_in[1];
    const float* fus  = (const float*)d_in[2];
    const float* mask = (const float*)d_in[3];
    float* out = (float*)d_out;
    float* ws  = (float*)d_ws;

    GaussW gw;
    double g[9], s = 0.0;
    for (int i = 0; i < 9; ++i) {
        int x = i - 4;
        g[i] = exp(-(double)(x * x) / 4.5);
        s += g[i];
    }
    for (int i = 0; i < 9; ++i) gw.g[i] = (float)(g[i] / s);

    fuse_loss_kernel<<<NBLK, NT, 0, stream>>>(vis, ir, fus, mask, ws, gw);
    reduce_kernel<<<1, 256, 0, stream>>>(ws, out);
}

// Round 25
// 43.012 us; speedup vs baseline: 19.2656x; 19.2656x over previous
//
#include <hip/hip_runtime.h>
#include <cmath>

#define Hn 512
#define Wn 512
#define Bn 32
#define BANDS 16
#define BH 32                       // output rows per band
#define NBLK (Bn * BANDS)           // 512 blocks
#define NT 512                      // 1 thread per column

struct GaussW { float g[9]; };

__device__ __forceinline__ void load_row(
    const float* __restrict__ pir, const float* __restrict__ pvi,
    const float* __restrict__ pfu, int y, int x,
    float& a, float& v, float& f)
{
    bool ok = (unsigned)y < (unsigned)Hn;
    size_t o = ok ? ((size_t)y * Wn + x) : 0;
    float aa = pir[o], vv = pvi[o], ff = pfu[o];
    a = ok ? aa : 0.f;  v = ok ? vv : 0.f;  f = ok ? ff : 0.f;
}

__device__ __forceinline__ void stage_row(
    float4* rowq, float* rowpd, int x, float a, float v, float f)
{
    float di = a - f, dv = v - f;
    rowq [x + 4] = make_float4(a, v, di * di, dv * dv);
    rowpd[x + 4] = (a - v) * (a + v);          // a^2 - v^2
}

// one image row: horizontal 9-tap from LDS + in-register vertical update.
// j, emit are compile-time constants after full unroll (rule #20).
__device__ __forceinline__ void compute_row(
    const float4* rowq, const float* rowpd, int x, int j, bool emit,
    float mk, const GaussW& gw,
    float* hb_i, float* hb_v, float* ag_i, float* ag_v, float* ag_q,
    float& Sbi, float& Sbv, float& acc)
{
    float bi = 0.f, bv = 0.f, ga = 0.f, gv = 0.f, qd = 0.f;
    #pragma unroll
    for (int i = 0; i < 9; ++i) {
        float4 q = rowq[x + i];
        float pd = rowpd[x + i];
        float gg = gw.g[i];
        bi += q.z;  bv += q.w;
        ga = fmaf(gg, q.x, ga);
        gv = fmaf(gg, q.y, gv);
        qd = fmaf(gg, pd, qd);
    }
    // vertical box: telescoping 9-row window
    Sbi += bi - hb_i[j];  hb_i[j] = bi;
    Sbv += bv - hb_v[j];  hb_v[j] = bv;
    // vertical gauss: 9 phase-rotating slots (R6-verified weights)
    float mi = 0.f, mv = 0.f, mq = 0.f;
    const float g8 = gw.g[8];
    #pragma unroll
    for (int s = 0; s < 9; ++s) {
        if (s == j) {
            mi = fmaf(g8, ga, ag_i[j]);
            mv = fmaf(g8, gv, ag_v[j]);
            mq = fmaf(g8, qd, ag_q[j]);
        } else {
            float w = gw.g[(j - s - 1 + 9) % 9];
            ag_i[s] = fmaf(w, ga, ag_i[s]);
            ag_v[s] = fmaf(w, gv, ag_v[s]);
            ag_q[s] = fmaf(w, qd, ag_q[s]);
        }
    }
    ag_i[j] = 0.f; ag_v[j] = 0.f; ag_q[j] = 0.f;
    if (emit) {
        float dvar = mq - (mi - mv) * (mi + mv);   // var_i - var_v (R15-verified)
        float m1  = (dvar > 0.f) ? 1.f : 0.f;
        float sel = (m1 + mk > 0.f) ? 1.f : 0.f;
        acc += sel * (Sbi * (1.f / 81.f)) + (1.f - sel) * (Sbv * (1.f / 81.f));
    }
}

// R25 = R20 verbatim (best verified: 42.7us scored, VGPR 128, 0 conflicts,
// 0 spill). R21-R24 post-mortems: the band structure's register budget is
// saturated (45 state + 6 staging + ~60 working); every variation either
// spilled (R21 +6 regs, R24 +6 regs -> 600-830us), was null (R22 b32 cut),
// or isomorphic (R23 reorder). This structure is the practical optimum for
// the separable-conv decomposition at this register budget.
__global__ __launch_bounds__(NT) void fuse_loss_kernel(
    const float* __restrict__ vis, const float* __restrict__ ir,
    const float* __restrict__ fus, const float* __restrict__ mask,
    float* __restrict__ ws, GaussW gw)
{
    __shared__ __align__(16) float4 s_q [2][2][Wn + 8];   // (a,v,d2i,d2v) 33280 B
    __shared__ float  s_pd[2][2][Wn + 8];                 // a^2-v^2        8320 B
    __shared__ float  s_part[8];

    const int t    = threadIdx.x;                 // column x
    const int img  = blockIdx.x >> 4;
    const int band = blockIdx.x & 15;
    const int Y0   = band * BH;
    const size_t ibase = (size_t)img * (size_t)(Hn * Wn);
    const float* pir = ir  + ibase;
    const float* pvi = vis + ibase;
    const float* pfu = fus + ibase;
    const float* pmk = mask + ibase;

    // zero the 4-px horizontal halos once (stage never touches them)
    if (t < 32) {
        int b = (t >> 4) & 1, rr = (t >> 3) & 1, e = t & 7;
        int col = (e < 4) ? e : (Wn + e);         // 0..3, 516..519
        s_q [b][rr][col] = make_float4(0.f, 0.f, 0.f, 0.f);
        s_pd[b][rr][col] = 0.f;
    }

    // vertical state (all statically indexed after unroll)
    float hb_i[9], hb_v[9], ag_i[9], ag_v[9], ag_q[9];
    #pragma unroll
    for (int s = 0; s < 9; ++s) {
        hb_i[s] = 0.f; hb_v[s] = 0.f;
        ag_i[s] = 0.f; ag_v[s] = 0.f; ag_q[s] = 0.f;
    }
    float Sbi = 0.f, Sbv = 0.f, acc = 0.f;

    // prologue: rows r=0,1 -> buf0; issue loads for rows r=2,3
    float aA, vA, fA, aB, vB, fB;
    load_row(pir, pvi, pfu, Y0 - 4, t, aA, vA, fA);
    load_row(pir, pvi, pfu, Y0 - 3, t, aB, vB, fB);
    stage_row(s_q[0][0], s_pd[0][0], t, aA, vA, fA);
    stage_row(s_q[0][1], s_pd[0][1], t, aB, vB, fB);
    load_row(pir, pvi, pfu, Y0 - 2, t, aA, vA, fA);
    load_row(pir, pvi, pfu, Y0 - 1, t, aB, vB, fB);
    float mkA = 0.f, mkB = 0.f;
    __syncthreads();

    #pragma unroll
    for (int p = 0; p < 20; ++p) {
        const int cur = p & 1;
        // stage rows 2p+2, 2p+3 (preloaded last iter) into the other buffer
        if (p < 19) {
            stage_row(s_q[cur ^ 1][0], s_pd[cur ^ 1][0], t, aA, vA, fA);
            stage_row(s_q[cur ^ 1][1], s_pd[cur ^ 1][1], t, aB, vB, fB);
        }
        // issue loads for rows 2p+4, 2p+5 (consumed next iter)
        if (p < 18) {
            load_row(pir, pvi, pfu, Y0 + 2 * p,     t, aA, vA, fA);
            load_row(pir, pvi, pfu, Y0 + 2 * p + 1, t, aB, vB, fB);
        }
        // compute rows r=2p, 2p+1 from buf[cur]; emit when r>=8
        compute_row(s_q[cur][0], s_pd[cur][0], t, (2 * p) % 9,  (p >= 4),
                    mkA, gw, hb_i, hb_v, ag_i, ag_v, ag_q, Sbi, Sbv, acc);
        compute_row(s_q[cur][1], s_pd[cur][1], t, (2 * p + 1) % 9, (p >= 4),
                    mkB, gw, hb_i, hb_v, ag_i, ag_v, ag_q, Sbi, Sbv, acc);
        // issue mask loads for pair p+1's emit rows
        if (p >= 3 && p < 19) {
            mkA = pmk[(size_t)(Y0 + 2 * p - 6) * Wn + t];
            mkB = pmk[(size_t)(Y0 + 2 * p - 5) * Wn + t];
        }
        __syncthreads();
    }

    // block reduction -> one partial per block
    #pragma unroll
    for (int off = 32; off > 0; off >>= 1)
        acc += __shfl_down(acc, off, 64);
    if ((t & 63) == 0) s_part[t >> 6] = acc;
    __syncthreads();
    if (t == 0) {
        float s = 0.f;
        #pragma unroll
        for (int i = 0; i < 8; ++i) s += s_part[i];
        ws[blockIdx.x] = s;
    }
}

__global__ __launch_bounds__(256) void reduce_kernel(const float* __restrict__ ws,
                                                     float* __restrict__ out)
{
    __shared__ float sp[4];
    int t = threadIdx.x;
    float v = 0.f;
    for (int i = t; i < NBLK; i += 256) v += ws[i];
    #pragma unroll
    for (int off = 32; off > 0; off >>= 1)
        v += __shfl_down(v, off, 64);
    if ((t & 63) == 0) sp[t >> 6] = v;
    __syncthreads();
    if (t == 0)
        out[0] = (sp[0] + sp[1] + sp[2] + sp[3]) * (1.f / ((float)Bn * Hn * Wn));
}

extern "C" void kernel_launch(void* const* d_in, const int* in_sizes, int n_in,
                              void* d_out, int out_size, void* d_ws, size_t ws_size,
                              hipStream_t stream) {
    const float* vis  = (const float*)d_in[0];
    const float* ir   = (const float*)d_in[1];
    const float* fus  = (const float*)d_in[2];
    const float* mask = (const float*)d_in[3];
    float* out = (float*)d_out;
    float* ws  = (float*)d_ws;

    GaussW gw;
    double g[9], s = 0.0;
    for (int i = 0; i < 9; ++i) {
        int x = i - 4;
        g[i] = exp(-(double)(x * x) / 4.5);
        s += g[i];
    }
    for (int i = 0; i < 9; ++i) gw.g[i] = (float)(g[i] / s);

    fuse_loss_kernel<<<NBLK, NT, 0, stream>>>(vis, ir, fus, mask, ws, gw);
    reduce_kernel<<<1, 256, 0, stream>>>(ws, out);
}